// Round 6
// baseline (214.651 us; speedup 1.0000x reference)
//
#include <hip/hip_runtime.h>

#define U_CNT 16384
#define I_CNT 8192
#define DIM 64
#define BAND 16                   // output rows per gemm block
#define WCHUNK 1024               // wide-chunk cols buffered in LDS before storing
#define NWCHUNK (I_CNT / WCHUNK)  // 8
#define NEG_LOG2E (-1.4426950408889634f)

typedef __bf16 bf16x8 __attribute__((ext_vector_type(8)));
typedef float f32x4 __attribute__((ext_vector_type(4)));

__device__ __forceinline__ unsigned short f32_to_bf16_rtn(float f) {
    unsigned int b = __float_as_uint(f);
    b += 0x7fffu + ((b >> 16) & 1u);
    return (unsigned short)(b >> 16);
}

// Prep: blocks [0, 2048) convert Q1 -> bf16; blocks [2048, ...) scan seg_ids
// for segment boundaries (every user has >=1 item -> every bounds[u] written
// exactly once; bounds[U_CNT] = nnz).
__global__ __launch_bounds__(256) void prep_kernel(
    const float* __restrict__ Q1, unsigned short* __restrict__ Q1bf,
    const int* __restrict__ segs, int nnz, int* __restrict__ bounds)
{
    if (blockIdx.x < 2048) {
        int i = blockIdx.x * 256 + threadIdx.x;   // covers I_CNT*DIM = 524288
        Q1bf[i] = f32_to_bf16_rtn(Q1[i]);
    } else {
        int i = (blockIdx.x - 2048) * 256 + threadIdx.x;
        if (i >= nnz) return;
        if (i == 0) bounds[segs[0]] = 0;
        else if (segs[i] != segs[i - 1]) bounds[segs[i]] = i;
        if (i == nnz - 1) bounds[U_CNT] = nnz;
    }
}

// One wave per user: read precomputed bounds, sum Q2 rows (lane = dim),
// scale by rsqrt(count), add P, write bf16 A-matrix. Gather unrolled x4.
__global__ __launch_bounds__(256) void pfull_kernel(
    const float* __restrict__ Q2, const float* __restrict__ P,
    const int* __restrict__ items, const int* __restrict__ bounds,
    unsigned short* __restrict__ Pbf)
{
    int u = (blockIdx.x * 256 + threadIdx.x) >> 6;
    int lane = threadIdx.x & 63;
    if (u >= U_CNT) return;
    int start = bounds[u];
    int end   = bounds[u + 1];

    float s = 0.f;
    int j = start;
    for (; j + 3 < end; j += 4) {
        int i0 = items[j], i1 = items[j + 1], i2 = items[j + 2], i3 = items[j + 3];
        float v0 = Q2[i0 * DIM + lane];
        float v1 = Q2[i1 * DIM + lane];
        float v2 = Q2[i2 * DIM + lane];
        float v3 = Q2[i3 * DIM + lane];
        s += (v0 + v1) + (v2 + v3);
    }
    for (; j < end; ++j) s += Q2[items[j] * DIM + lane];

    int cnt = end - start;              // guaranteed >= 1
    float val = s * rsqrtf((float)cnt) + P[u * DIM + lane];
    Pbf[u * DIM + lane] = f32_to_bf16_rtn(val);
}

// Band-sweep GEMM + sigmoid. Block = 16-row band x 8192 cols, swept in 8
// wide-chunks of 1024 cols (phase-staggered). Each wide-chunk: 4 sub-tiles
// of 256 cols computed into a block-wide LDS tile [16][1024] (exactly 64KB,
// XOR-swizzled), then a store phase writing each output row's 4KB
// CONTIGUOUSLY (4 x 1KB b128 instrs back-to-back per row). 4x fewer
// row-visits at 4x the granule vs round-3 -> amortizes DRAM row activates
// (the hypothesized 2x write-BW gap vs the linear fill). Plain stores (nt
// measured -10us). Two barriers per wide-chunk.
__global__ __launch_bounds__(256) void gemm_sig_kernel(
    const unsigned short* __restrict__ Abf, const unsigned short* __restrict__ Bbf,
    const float* __restrict__ bu, const float* __restrict__ bi,
    float* __restrict__ out)
{
    const int lane = threadIdx.x & 63;
    const int wid  = threadIdx.x >> 6;      // 0..3
    const int r = lane & 15, g = lane >> 4;
    const int band = blockIdx.x * BAND;

    __shared__ float lds[BAND][WCHUNK];     // 64 KB; col ^ ((row>>2)<<4) swizzle

    // A fragments for the whole band (rows band..band+15), both K-steps.
    bf16x8 a[2];
#pragma unroll
    for (int ks = 0; ks < 2; ++ks)
        a[ks] = *reinterpret_cast<const bf16x8*>(&Abf[(band + r) * DIM + ks * 32 + g * 8]);

    // bu for the 4 acc rows this lane holds (tile row = g*4 + j), pre-biased.
    float bu_g[4];
#pragma unroll
    for (int j = 0; j < 4; ++j) bu_g[j] = bu[band + g * 4 + j] + 0.05f;

    const int c0 = (blockIdx.x * 3) & (NWCHUNK - 1);

    for (int cc = 0; cc < NWCHUNK; ++cc) {
        const int c = (cc + c0) & (NWCHUNK - 1);
        const int colbase = c * WCHUNK;

        // Compute 4 sub-tiles of 256 cols into the LDS tile.
#pragma unroll
        for (int sub = 0; sub < 4; ++sub) {
            const int col0 = colbase + sub * 256 + wid * 64;

            bf16x8 b[4][2];
            float bi_f[4];
#pragma unroll
            for (int nf = 0; nf < 4; ++nf) {
                bi_f[nf] = bi[col0 + nf * 16 + r];
#pragma unroll
                for (int ks = 0; ks < 2; ++ks)
                    b[nf][ks] = *reinterpret_cast<const bf16x8*>(
                        &Bbf[(col0 + nf * 16 + r) * DIM + ks * 32 + g * 8]);
            }

            f32x4 acc[4] = {};
#pragma unroll
            for (int ks = 0; ks < 2; ++ks)
#pragma unroll
                for (int nf = 0; nf < 4; ++nf)
                    acc[nf] = __builtin_amdgcn_mfma_f32_16x16x32_bf16(
                        a[ks], b[nf][ks], acc[nf], 0, 0, 0);

            // Sigmoid in acc layout (row = g*4+j, col = sub*256+wid*64+nf*16+r),
            // write into swizzled LDS: col ^ (g<<4) -> 2-way banks (free).
#pragma unroll
            for (int nf = 0; nf < 4; ++nf)
#pragma unroll
                for (int j = 0; j < 4; ++j) {
                    float x = (acc[nf][j] + bu_g[j] + bi_f[nf]) * NEG_LOG2E;
                    float e = __builtin_amdgcn_exp2f(x);
                    float v = 5.f * __builtin_amdgcn_rcpf(1.f + e);
                    int colq = (sub * 256 + wid * 64 + nf * 16 + r) ^ (g << 4);
                    lds[g * 4 + j][colq] = v;
                }
        }

        __syncthreads();

        // Store phase: wave wid owns rows wid*4..wid*4+3; per row, 4 x 1KB
        // contiguous b128 stores back-to-back = 4KB contiguous per row-visit.
        // Read swizzle matches write ((row>>2)<<4 == wid<<4 here); XOR hits
        // float-idx bits 4-5 only, so each lane's 16B stays contiguous and
        // row-uniform XOR keeps the read conflict-free.
#pragma unroll
        for (int i = 0; i < 4; ++i) {
            const int row = wid * 4 + i;
#pragma unroll
            for (int q = 0; q < 4; ++q) {
                int idx = (q * 256 + lane * 4) ^ (wid << 4);
                f32x4 v = *reinterpret_cast<const f32x4*>(&lds[row][idx]);
                *reinterpret_cast<f32x4*>(
                    &out[(size_t)(band + row) * I_CNT + colbase + q * 256 + lane * 4]) = v;
            }
        }

        __syncthreads();   // protect LDS reuse by next wide-chunk
    }
}

extern "C" void kernel_launch(void* const* d_in, const int* in_sizes, int n_in,
                              void* d_out, int out_size, void* d_ws, size_t ws_size,
                              hipStream_t stream)
{
    const float* Q1 = (const float*)d_in[0];
    const float* Q2 = (const float*)d_in[1];
    const float* P  = (const float*)d_in[2];
    const float* bu = (const float*)d_in[3];
    const float* bi = (const float*)d_in[4];
    const int* items = (const int*)d_in[5];
    const int* segs  = (const int*)d_in[6];
    const int nnz = in_sizes[5];

    unsigned short* Pbf  = (unsigned short*)d_ws;            // 2 MB
    unsigned short* Q1bf = Pbf + U_CNT * DIM;                // 1 MB
    int* bounds = (int*)(Q1bf + I_CNT * DIM);                // 64 KB + 4 B

    int boundsBlocks = (nnz + 255) / 256;
    prep_kernel<<<2048 + boundsBlocks, 256, 0, stream>>>(Q1, Q1bf, segs, nnz, bounds);
    pfull_kernel<<<U_CNT / 4, 256, 0, stream>>>(Q2, P, items, bounds, Pbf);
    gemm_sig_kernel<<<U_CNT / BAND, 256, 0, stream>>>(Pbf, Q1bf, bu, bi, (float*)d_out);
}

// Round 7
// 175.301 us; speedup vs baseline: 1.2245x; 1.2245x over previous
//
#include <hip/hip_runtime.h>

#define U_CNT 16384
#define I_CNT 8192
#define DIM 64
#define BAND 16                   // output rows per gemm block
#define CHUNK 256                 // output cols per chunk iteration
#define NCHUNK (I_CNT / CHUNK)    // 32
#define LDS_STRIDE 68             // floats; 68 % 32 == 4 -> 2-way conflicts only (free)

typedef __bf16 bf16x8 __attribute__((ext_vector_type(8)));
typedef float f32x4 __attribute__((ext_vector_type(4)));

__device__ __forceinline__ unsigned short f32_to_bf16_rtn(float f) {
    unsigned int b = __float_as_uint(f);
    b += 0x7fffu + ((b >> 16) & 1u);
    return (unsigned short)(b >> 16);
}

// Prep: blocks [0, 2048) convert Q1 -> bf16; blocks [2048, ...) scan seg_ids
// for segment boundaries (every user has >=1 item -> every bounds[u] written
// exactly once; bounds[U_CNT] = nnz).
__global__ __launch_bounds__(256) void prep_kernel(
    const float* __restrict__ Q1, unsigned short* __restrict__ Q1bf,
    const int* __restrict__ segs, int nnz, int* __restrict__ bounds)
{
    if (blockIdx.x < 2048) {
        int i = blockIdx.x * 256 + threadIdx.x;   // covers I_CNT*DIM = 524288
        Q1bf[i] = f32_to_bf16_rtn(Q1[i]);
    } else {
        int i = (blockIdx.x - 2048) * 256 + threadIdx.x;
        if (i >= nnz) return;
        if (i == 0) bounds[segs[0]] = 0;
        else if (segs[i] != segs[i - 1]) bounds[segs[i]] = i;
        if (i == nnz - 1) bounds[U_CNT] = nnz;
    }
}

// One wave per user: read precomputed bounds, sum Q2 rows (lane = dim),
// scale by rsqrt(count), add P, write bf16 A-matrix. Gather unrolled x4.
__global__ __launch_bounds__(256) void pfull_kernel(
    const float* __restrict__ Q2, const float* __restrict__ P,
    const int* __restrict__ items, const int* __restrict__ bounds,
    unsigned short* __restrict__ Pbf)
{
    int u = (blockIdx.x * 256 + threadIdx.x) >> 6;
    int lane = threadIdx.x & 63;
    if (u >= U_CNT) return;
    int start = bounds[u];
    int end   = bounds[u + 1];

    float s = 0.f;
    int j = start;
    for (; j + 3 < end; j += 4) {
        int i0 = items[j], i1 = items[j + 1], i2 = items[j + 2], i3 = items[j + 3];
        float v0 = Q2[i0 * DIM + lane];
        float v1 = Q2[i1 * DIM + lane];
        float v2 = Q2[i2 * DIM + lane];
        float v3 = Q2[i3 * DIM + lane];
        s += (v0 + v1) + (v2 + v3);
    }
    for (; j < end; ++j) s += Q2[items[j] * DIM + lane];

    int cnt = end - start;              // guaranteed >= 1
    float val = s * rsqrtf((float)cnt) + P[u * DIM + lane];
    Pbf[u * DIM + lane] = f32_to_bf16_rtn(val);
}

// Band-sweep GEMM + sigmoid epilogue — EXACT copy of the 186us champion
// (round-3 measurement), with ONE change: output stores are nontemporal.
// Clean A/B for the cached-store-path theory: write-allocate cycles 536MB
// through L2/L3 and HBM is fed by eviction order (~3.6 TB/s effective);
// nt bypasses allocation so HBM sees program order (fill kernel: 6.7 TB/s).
__global__ __launch_bounds__(256) void gemm_sig_kernel(
    const unsigned short* __restrict__ Abf, const unsigned short* __restrict__ Bbf,
    const float* __restrict__ bu, const float* __restrict__ bi,
    float* __restrict__ out)
{
    const int lane = threadIdx.x & 63;
    const int wid  = threadIdx.x >> 6;      // 0..3: 64-col sub-band within chunk
    const int r = lane & 15, g = lane >> 4;
    const int band = blockIdx.x * BAND;

    __shared__ float lds_all[4][BAND * LDS_STRIDE];
    float* lds = lds_all[wid];              // per-wave private region

    bf16x8 a[2];
#pragma unroll
    for (int ks = 0; ks < 2; ++ks)
        a[ks] = *reinterpret_cast<const bf16x8*>(&Abf[(band + r) * DIM + ks * 32 + g * 8]);

    float bu_g[4];
#pragma unroll
    for (int j = 0; j < 4; ++j) bu_g[j] = bu[band + g * 4 + j];

    const int c0 = (blockIdx.x * 7) & (NCHUNK - 1);

    for (int cc = 0; cc < NCHUNK; ++cc) {
        const int c = (cc + c0) & (NCHUNK - 1);
        const int col0 = c * CHUNK + wid * 64;

        bf16x8 b[4][2];
        float bi_f[4];
#pragma unroll
        for (int nf = 0; nf < 4; ++nf) {
            bi_f[nf] = bi[col0 + nf * 16 + r];
#pragma unroll
            for (int ks = 0; ks < 2; ++ks)
                b[nf][ks] = *reinterpret_cast<const bf16x8*>(
                    &Bbf[(col0 + nf * 16 + r) * DIM + ks * 32 + g * 8]);
        }

        f32x4 acc[4] = {};
#pragma unroll
        for (int ks = 0; ks < 2; ++ks)
#pragma unroll
            for (int nf = 0; nf < 4; ++nf)
                acc[nf] = __builtin_amdgcn_mfma_f32_16x16x32_bf16(
                    a[ks], b[nf][ks], acc[nf], 0, 0, 0);

        // Sigmoid in acc layout, then transpose finished values through LDS.
#pragma unroll
        for (int nf = 0; nf < 4; ++nf)
#pragma unroll
            for (int j = 0; j < 4; ++j) {
                float x = acc[nf][j] + bu_g[j] + bi_f[nf] + 0.05f;
                float v = 5.f * __builtin_amdgcn_rcpf(1.f + __expf(-x));
                lds[(g * 4 + j) * LDS_STRIDE + nf * 16 + r] = v;
            }

        // Read back row-major (compiler inserts the lgkmcnt wait): instr i
        // covers rows i*4..i*4+3, 256B contiguous per row, full cache lines.
#pragma unroll
        for (int i = 0; i < 4; ++i) {
            const int row = i * 4 + g;
            f32x4 v = *reinterpret_cast<const f32x4*>(&lds[row * LDS_STRIDE + r * 4]);
            __builtin_nontemporal_store(v, reinterpret_cast<f32x4*>(
                &out[(size_t)(band + row) * I_CNT + col0 + r * 4]));
        }
    }
}

extern "C" void kernel_launch(void* const* d_in, const int* in_sizes, int n_in,
                              void* d_out, int out_size, void* d_ws, size_t ws_size,
                              hipStream_t stream)
{
    const float* Q1 = (const float*)d_in[0];
    const float* Q2 = (const float*)d_in[1];
    const float* P  = (const float*)d_in[2];
    const float* bu = (const float*)d_in[3];
    const float* bi = (const float*)d_in[4];
    const int* items = (const int*)d_in[5];
    const int* segs  = (const int*)d_in[6];
    const int nnz = in_sizes[5];

    unsigned short* Pbf  = (unsigned short*)d_ws;            // 2 MB
    unsigned short* Q1bf = Pbf + U_CNT * DIM;                // 1 MB
    int* bounds = (int*)(Q1bf + I_CNT * DIM);                // 64 KB + 4 B

    int boundsBlocks = (nnz + 255) / 256;
    prep_kernel<<<2048 + boundsBlocks, 256, 0, stream>>>(Q1, Q1bf, segs, nnz, bounds);
    pfull_kernel<<<U_CNT / 4, 256, 0, stream>>>(Q2, P, items, bounds, Pbf);
    gemm_sig_kernel<<<U_CNT / BAND, 256, 0, stream>>>(Pbf, Q1bf, bu, bi, (float*)d_out);
}

// Round 9
// 130.576 us; speedup vs baseline: 1.6439x; 1.3425x over previous
//
#include <hip/hip_runtime.h>

#define U_CNT 16384
#define I_CNT 8192
#define DIM 64
#define BAND 16                   // rows per band (per block per step)
#define CHUNK 256                 // cols owned by one block (fixed)
#define NSTEP 32                  // bands per group sweep
#define LDS_STRIDE 68             // floats; 68 % 32 == 4 -> 2-way conflicts only (free)
#define NEG_LOG2E (-1.4426950408889634f)

typedef __bf16 bf16x8 __attribute__((ext_vector_type(8)));
typedef float f32x4 __attribute__((ext_vector_type(4)));

__device__ __forceinline__ unsigned short f32_to_bf16_rtn(float f) {
    unsigned int b = __float_as_uint(f);
    b += 0x7fffu + ((b >> 16) & 1u);
    return (unsigned short)(b >> 16);
}

// Prep: blocks [0, 2048) convert Q1 -> bf16; blocks [2048, ...) scan seg_ids
// for segment boundaries (every user has >=1 item -> every bounds[u] written
// exactly once; bounds[U_CNT] = nnz).
__global__ __launch_bounds__(256) void prep_kernel(
    const float* __restrict__ Q1, unsigned short* __restrict__ Q1bf,
    const int* __restrict__ segs, int nnz, int* __restrict__ bounds)
{
    if (blockIdx.x < 2048) {
        int i = blockIdx.x * 256 + threadIdx.x;   // covers I_CNT*DIM = 524288
        Q1bf[i] = f32_to_bf16_rtn(Q1[i]);
    } else {
        int i = (blockIdx.x - 2048) * 256 + threadIdx.x;
        if (i >= nnz) return;
        if (i == 0) bounds[segs[0]] = 0;
        else if (segs[i] != segs[i - 1]) bounds[segs[i]] = i;
        if (i == nnz - 1) bounds[U_CNT] = nnz;
    }
}

// One wave per user: read precomputed bounds, sum Q2 rows (lane = dim),
// scale by rsqrt(count), add P, write bf16 A-matrix. Gather unrolled x4.
__global__ __launch_bounds__(256) void pfull_kernel(
    const float* __restrict__ Q2, const float* __restrict__ P,
    const int* __restrict__ items, const int* __restrict__ bounds,
    unsigned short* __restrict__ Pbf)
{
    int u = (blockIdx.x * 256 + threadIdx.x) >> 6;
    int lane = threadIdx.x & 63;
    if (u >= U_CNT) return;
    int start = bounds[u];
    int end   = bounds[u + 1];

    float s = 0.f;
    int j = start;
    for (; j + 3 < end; j += 4) {
        int i0 = items[j], i1 = items[j + 1], i2 = items[j + 2], i3 = items[j + 3];
        float v0 = Q2[i0 * DIM + lane];
        float v1 = Q2[i1 * DIM + lane];
        float v2 = Q2[i2 * DIM + lane];
        float v3 = Q2[i3 * DIM + lane];
        s += (v0 + v1) + (v2 + v3);
    }
    for (; j < end; ++j) s += Q2[items[j] * DIM + lane];

    int cnt = end - start;              // guaranteed >= 1
    float val = s * rsqrtf((float)cnt) + P[u * DIM + lane];
    Pbf[u * DIM + lane] = f32_to_bf16_rtn(val);
}

// Coordinated-window GEMM + sigmoid. GRID = 1024 BLOCKS (32 groups x 32
// members) — round-8's crash was a 32x-oversized grid, OOB on out/Abf.
// Block b: member = b&31 owns FIXED cols [member*256, +256); group = b>>5.
// Step s: block processes band (group + s*32) = rows [(group+s*32)*16, +16).
// At step s the 32 members of each group write one band densely across all
// 8192 cols, and the 32 groups cover rows [s*512, +512): the GPU-wide write
// set is a CONTIGUOUS 16 MB window sweeping linearly (fill-kernel shape)
// instead of 16K private 1KB-granule streams scattered over 536 MB. Loose
// lockstep from uniform per-step work; drift only widens the window.
// B fragments + bi register-resident (loaded once); per step only the
// 2-instr A fragment + bu reload. Epilogue identical to the 175us champion:
// sigmoid in acc layout, per-wave-private LDS transpose, 4 nontemporal
// 256B-per-row store instructions.
__global__ __launch_bounds__(256) void gemm_sig_kernel(
    const unsigned short* __restrict__ Abf, const unsigned short* __restrict__ Bbf,
    const float* __restrict__ bu, const float* __restrict__ bi,
    float* __restrict__ out)
{
    const int lane = threadIdx.x & 63;
    const int wid  = threadIdx.x >> 6;      // 0..3: 64-col sub-band within chunk
    const int r = lane & 15, g = lane >> 4;
    const int member = blockIdx.x & 31;     // fixed col chunk
    const int group  = blockIdx.x >> 5;     // 0..31
    const int col0 = member * CHUNK + wid * 64;

    __shared__ float lds_all[4][BAND * LDS_STRIDE];
    float* lds = lds_all[wid];              // per-wave private region

    // B fragments + bi: loaded ONCE, register-resident for the whole kernel.
    bf16x8 b[4][2];
    float bi_f[4];
#pragma unroll
    for (int nf = 0; nf < 4; ++nf) {
        bi_f[nf] = bi[col0 + nf * 16 + r] + 0.05f;   // fold the +0.05 here
#pragma unroll
        for (int ks = 0; ks < 2; ++ks)
            b[nf][ks] = *reinterpret_cast<const bf16x8*>(
                &Bbf[(col0 + nf * 16 + r) * DIM + ks * 32 + g * 8]);
    }

    for (int s = 0; s < NSTEP; ++s) {
        const int band = (group + s * 32) * BAND;

        // A fragment for this band (rows band..band+15), both K-steps.
        bf16x8 a[2];
#pragma unroll
        for (int ks = 0; ks < 2; ++ks)
            a[ks] = *reinterpret_cast<const bf16x8*>(
                &Abf[(band + r) * DIM + ks * 32 + g * 8]);

        float bu_g[4];
#pragma unroll
        for (int j = 0; j < 4; ++j) bu_g[j] = bu[band + g * 4 + j];

        f32x4 acc[4] = {};
#pragma unroll
        for (int ks = 0; ks < 2; ++ks)
#pragma unroll
            for (int nf = 0; nf < 4; ++nf)
                acc[nf] = __builtin_amdgcn_mfma_f32_16x16x32_bf16(
                    a[ks], b[nf][ks], acc[nf], 0, 0, 0);

        // Sigmoid in acc layout (row = g*4+j, col = nf*16+r), then transpose
        // through per-wave LDS.
#pragma unroll
        for (int nf = 0; nf < 4; ++nf)
#pragma unroll
            for (int j = 0; j < 4; ++j) {
                float x = (acc[nf][j] + bu_g[j] + bi_f[nf]) * NEG_LOG2E;
                float e = __builtin_amdgcn_exp2f(x);
                float v = 5.f * __builtin_amdgcn_rcpf(1.f + e);
                lds[(g * 4 + j) * LDS_STRIDE + nf * 16 + r] = v;
            }

        // Store: instr i covers rows i*4..i*4+3 (g picks row, r picks 16B
        // slot): 256B contiguous per row, full cache lines, nontemporal.
#pragma unroll
        for (int i = 0; i < 4; ++i) {
            const int row = i * 4 + g;
            f32x4 v = *reinterpret_cast<const f32x4*>(&lds[row * LDS_STRIDE + r * 4]);
            __builtin_nontemporal_store(v, reinterpret_cast<f32x4*>(
                &out[(size_t)(band + row) * I_CNT + col0 + r * 4]));
        }
    }
}

extern "C" void kernel_launch(void* const* d_in, const int* in_sizes, int n_in,
                              void* d_out, int out_size, void* d_ws, size_t ws_size,
                              hipStream_t stream)
{
    const float* Q1 = (const float*)d_in[0];
    const float* Q2 = (const float*)d_in[1];
    const float* P  = (const float*)d_in[2];
    const float* bu = (const float*)d_in[3];
    const float* bi = (const float*)d_in[4];
    const int* items = (const int*)d_in[5];
    const int* segs  = (const int*)d_in[6];
    const int nnz = in_sizes[5];

    unsigned short* Pbf  = (unsigned short*)d_ws;            // 2 MB
    unsigned short* Q1bf = Pbf + U_CNT * DIM;                // 1 MB
    int* bounds = (int*)(Q1bf + I_CNT * DIM);                // 64 KB + 4 B

    int boundsBlocks = (nnz + 255) / 256;
    prep_kernel<<<2048 + boundsBlocks, 256, 0, stream>>>(Q1, Q1bf, segs, nnz, bounds);
    pfull_kernel<<<U_CNT / 4, 256, 0, stream>>>(Q2, P, items, bounds, Pbf);
    // 32 groups x 32 members = 1024 blocks; each block sweeps NSTEP=32 bands.
    gemm_sig_kernel<<<32 * 32, 256, 0, stream>>>(Pbf, Q1bf, bu, bi, (float*)d_out);
}